// Round 11
// baseline (124.399 us; speedup 1.0000x reference)
//
#include <hip/hip_runtime.h>
#include <hip/hip_bf16.h>
#include <stdint.h>

#define BATCH 4
#define CCH   64
#define NPIX  4096
#define DQK   8
#define PXB   128

typedef __attribute__((ext_vector_type(8)))  short bf16x8;
typedef __attribute__((ext_vector_type(16))) float f32x16;
typedef __attribute__((ext_vector_type(4)))  uint32_t u32x4;

static __device__ __forceinline__ short f2bf(float f) {
    union { __hip_bfloat16 h; short s; } u;
    u.h = __float2bfloat16(f);
    return u.s;
}
static __device__ __forceinline__ uint32_t cvt_pk_bf16(float lo, float hi) {
    uint32_t r;
    asm("v_cvt_pk_bf16_f32 %0, %1, %2" : "=v"(r) : "v"(lo), "v"(hi));
    return r;
}

// ---------------------------------------------------------------------------
// Projection: q = (Wq x + bq)*scale*log2e, k = Wk x + bk, v = Wv x + bv
// q,k: [B][N][16] bf16 (dims 8..15 zero); v: [B][C][N] bf16.
// ---------------------------------------------------------------------------
__global__ __launch_bounds__(256) void proj_kernel(
    const float* __restrict__ x,
    const float* __restrict__ Wq, const float* __restrict__ bq,
    const float* __restrict__ Wk, const float* __restrict__ bk,
    const float* __restrict__ Wv, const float* __restrict__ bv,
    short* __restrict__ qo, short* __restrict__ ko, short* __restrict__ vo)
{
    __shared__ float xs[CCH][PXB];     // 32 KB
    __shared__ float wv_s[CCH][68];    // transposed [c][e], padded rows
    __shared__ float wq_s[CCH][DQK];
    __shared__ float wk_s[CCH][DQK];

    const int b  = blockIdx.x >> 5;
    const int n0 = (blockIdx.x & 31) * PXB;
    const int tid = threadIdx.x;

    for (int i = tid; i < CCH*CCH; i += 256) wv_s[i & 63][i >> 6] = Wv[i];
    for (int i = tid; i < CCH*DQK; i += 256) { wq_s[i & 63][i >> 6] = Wq[i]; wk_s[i & 63][i >> 6] = Wk[i]; }
    for (int i = tid; i < CCH*PXB; i += 256) {
        int c = i >> 7, p = i & 127;
        xs[c][p] = x[((size_t)b*CCH + c)*NPIX + n0 + p];
    }
    __syncthreads();

    const int p0 = tid & 31;
    const int g  = tid >> 5;       // 0..7: 8 v-channels + 1 q-dim + 1 k-dim
    const int e0 = g * 8;

    float av[4][8];
    float aq[4], ak[4];
    #pragma unroll
    for (int pi = 0; pi < 4; ++pi) {
        #pragma unroll
        for (int i = 0; i < 8; ++i) av[pi][i] = bv[e0 + i];
        aq[pi] = bq[g]; ak[pi] = bk[g];
    }

    for (int c = 0; c < CCH; ++c) {
        float4 w0 = *(const float4*)&wv_s[c][e0];
        float4 w1 = *(const float4*)&wv_s[c][e0 + 4];
        float wq = wq_s[c][g], wk = wk_s[c][g];
        #pragma unroll
        for (int pi = 0; pi < 4; ++pi) {
            float xv = xs[c][p0 + 32*pi];
            av[pi][0] += w0.x*xv; av[pi][1] += w0.y*xv;
            av[pi][2] += w0.z*xv; av[pi][3] += w0.w*xv;
            av[pi][4] += w1.x*xv; av[pi][5] += w1.y*xv;
            av[pi][6] += w1.z*xv; av[pi][7] += w1.w*xv;
            aq[pi] += wq*xv; ak[pi] += wk*xv;
        }
    }

    const float qscale = 0.51010407112635f;  // (1/sqrt(8)) * log2(e)
    const size_t vb = (size_t)b * CCH * NPIX;
    #pragma unroll
    for (int pi = 0; pi < 4; ++pi) {
        const int px = n0 + p0 + 32*pi;
        #pragma unroll
        for (int i = 0; i < 8; ++i)
            vo[vb + (size_t)(e0 + i)*NPIX + px] = f2bf(av[pi][i]);
        const size_t qb = ((size_t)b*NPIX + px)*16 + g;
        qo[qb]     = f2bf(aq[pi] * qscale);
        qo[qb + 8] = 0;
        ko[qb]     = f2bf(ak[pi]);
        ko[qb + 8] = 0;
    }
}

// ---------------------------------------------------------------------------
// Attention main: 2048 blocks x 256 thr (4 waves). Block = (batch, 32-query
// tile, 1024-wide j-chunk); each wave owns 256 j (8 tiles of 32). Occupancy:
// 33 KB LDS + VGPR<=128 -> 4 blocks/CU = 16 waves/CU (vs 2 blocks before).
// No max tracking (bounded scores, exp2 domain); in-block 4-wave sum merge;
// unnormalized partial [64][32] + l-partial [32] per block to ws.
// ---------------------------------------------------------------------------
__global__ __launch_bounds__(256, 4) void attn_main(
    const short* __restrict__ qg, const short* __restrict__ kg,
    const short* __restrict__ vg,
    float* __restrict__ part, float* __restrict__ lp)
{
    __shared__ float l_s[4][32];
    __shared__ float acc_s[4][CCH][32];   // 32 KB

    const int jc = blockIdx.x & 3;
    const int qt = (blockIdx.x >> 2) & 127;
    const int b  = blockIdx.x >> 9;
    const int i0 = qt << 5;
    const int tid  = threadIdx.x;
    const int wave = tid >> 6, lane = tid & 63;
    const int hi = lane >> 5, li = lane & 31;

    f32x16 z16;
    #pragma unroll
    for (int r = 0; r < 16; ++r) z16[r] = 0.f;

    // Q fragment (B-operand): col=li, k=hi*8+e (k=8..15 are stored zeros)
    const bf16x8 qf = *(const bf16x8*)&qg[((size_t)b*NPIX + i0 + li)*16 + hi*8];

    f32x16 acc0 = z16, acc1 = z16;
    float l_run = 0.f;               // lane-local partial (16 of 32 rows)

    const short* kp = kg + (size_t)b * NPIX * 16;
    const size_t vbase = (size_t)b * CCH * NPIX;
    const short* vrow0 = &vg[vbase + (size_t)li*NPIX];
    const short* vrow1 = vrow0 + (size_t)32*NPIX;

    const int jbeg = (jc << 10) + (wave << 8);
    #pragma unroll 2
    for (int t = 0; t < 8; ++t) {
        const int j0 = jbeg + t*32;

        bf16x8 akf = *(const bf16x8*)&kp[(size_t)(j0 + li)*16 + hi*8];
        f32x16 S = __builtin_amdgcn_mfma_f32_32x32x16_bf16(akf, qf, z16, 0, 0, 0);
        // lane holds S[j][i]: col i=li, rows j=(r&3)+8*(r>>2)+4*hi

        bf16x8 av00 = *(const bf16x8*)(vrow0 + j0 + hi*8);
        bf16x8 av01 = *(const bf16x8*)(vrow0 + j0 + 16 + hi*8);
        bf16x8 av10 = *(const bf16x8*)(vrow1 + j0 + hi*8);
        bf16x8 av11 = *(const bf16x8*)(vrow1 + j0 + 16 + hi*8);

        #pragma unroll
        for (int r = 0; r < 16; ++r) S[r] = __builtin_amdgcn_exp2f(S[r]);

        // lane-local l partial via add tree
        {
            float s0 = (S[0]+S[1]) + (S[2]+S[3]);
            float s1 = (S[4]+S[5]) + (S[6]+S[7]);
            float s2 = (S[8]+S[9]) + (S[10]+S[11]);
            float s3 = (S[12]+S[13]) + (S[14]+S[15]);
            l_run += (s0+s1) + (s2+s3);
        }

        // pack P -> bf16 B-fragments via cvt_pk + permlane32_swap (no LDS)
        uint32_t a01 = cvt_pk_bf16(S[0], S[1]);
        uint32_t a23 = cvt_pk_bf16(S[2], S[3]);
        uint32_t a45 = cvt_pk_bf16(S[4], S[5]);
        uint32_t a67 = cvt_pk_bf16(S[6], S[7]);
        uint32_t a89 = cvt_pk_bf16(S[8], S[9]);
        uint32_t aab = cvt_pk_bf16(S[10], S[11]);
        uint32_t acd = cvt_pk_bf16(S[12], S[13]);
        uint32_t aef = cvt_pk_bf16(S[14], S[15]);
        asm("v_permlane32_swap_b32 %0, %1" : "+v"(a01), "+v"(a45));
        asm("v_permlane32_swap_b32 %0, %1" : "+v"(a23), "+v"(a67));
        asm("v_permlane32_swap_b32 %0, %1" : "+v"(a89), "+v"(acd));
        asm("v_permlane32_swap_b32 %0, %1" : "+v"(aab), "+v"(aef));
        u32x4 pw0 = { a01, a23, a45, a67 };
        u32x4 pw1 = { a89, aab, acd, aef };
        bf16x8 b0 = __builtin_bit_cast(bf16x8, pw0);
        bf16x8 b1 = __builtin_bit_cast(bf16x8, pw1);

        __builtin_amdgcn_s_setprio(1);
        acc0 = __builtin_amdgcn_mfma_f32_32x32x16_bf16(av00, b0, acc0, 0, 0, 0);
        acc1 = __builtin_amdgcn_mfma_f32_32x32x16_bf16(av10, b0, acc1, 0, 0, 0);
        acc0 = __builtin_amdgcn_mfma_f32_32x32x16_bf16(av01, b1, acc0, 0, 0, 0);
        acc1 = __builtin_amdgcn_mfma_f32_32x32x16_bf16(av11, b1, acc1, 0, 0, 0);
        __builtin_amdgcn_s_setprio(0);
    }

    // ---- in-block 4-wave merge (plain sums) ----
    l_run += __shfl_xor(l_run, 32);
    if (hi == 0) l_s[wave][li] = l_run;
    #pragma unroll
    for (int r = 0; r < 16; ++r) {
        int row = (r & 3) + ((r >> 2) << 3) + (hi << 2);
        acc_s[wave][row][li]      = acc0[r];
        acc_s[wave][row + 32][li] = acc1[r];
    }
    __syncthreads();

    float* pb = part + ((size_t)blockIdx.x) * (CCH*32);
    for (int idx = tid; idx < CCH*32; idx += 256) {
        int c = idx >> 5, i = idx & 31;
        pb[idx] = acc_s[0][c][i] + acc_s[1][c][i] + acc_s[2][c][i] + acc_s[3][c][i];
    }
    if (tid < 32)
        lp[((size_t)blockIdx.x)*32 + tid] =
            l_s[0][tid] + l_s[1][tid] + l_s[2][tid] + l_s[3][tid];
}

// ---------------------------------------------------------------------------
// Merge: 512 blocks (b, qtile) x 256 thr. Sum the 4 j-chunk partials,
// normalize by 1/sum(l), apply gamma + residual.
// ---------------------------------------------------------------------------
__global__ __launch_bounds__(256) void merge_kernel(
    const float* __restrict__ part, const float* __restrict__ lp,
    const float* __restrict__ x, const float* __restrict__ gamma,
    float* __restrict__ outp)
{
    __shared__ float linv_s[32];

    const int qt = blockIdx.x & 127;
    const int b  = blockIdx.x >> 7;
    const int tid = threadIdx.x;

    const size_t base = ((size_t)blockIdx.x) * 4 * (CCH*32);   // 4 j-chunk partials
    const size_t lbase = ((size_t)blockIdx.x) * 4 * 32;

    if (tid < 32) {
        float L = lp[lbase + tid] + lp[lbase + 32 + tid]
                + lp[lbase + 64 + tid] + lp[lbase + 96 + tid];
        linv_s[tid] = __builtin_amdgcn_rcpf(L);
    }
    __syncthreads();

    const float g0 = gamma[0];
    const size_t vbase = (size_t)b * CCH * NPIX;
    const int i0 = qt << 5;
    for (int idx = tid; idx < CCH*32; idx += 256) {
        int c = idx >> 5, i = idx & 31;
        float s = part[base + idx] + part[base + 2048 + idx]
                + part[base + 4096 + idx] + part[base + 6144 + idx];
        size_t gidx = vbase + (size_t)c*NPIX + i0 + i;
        outp[gidx] = g0 * (s * linv_s[i]) + x[gidx];
    }
}

extern "C" void kernel_launch(void* const* d_in, const int* in_sizes, int n_in,
                              void* d_out, int out_size, void* d_ws, size_t ws_size,
                              hipStream_t stream) {
    const float* x     = (const float*)d_in[0];
    const float* Wq    = (const float*)d_in[1];
    const float* bq    = (const float*)d_in[2];
    const float* Wk    = (const float*)d_in[3];
    const float* bk    = (const float*)d_in[4];
    const float* Wv    = (const float*)d_in[5];
    const float* bv    = (const float*)d_in[6];
    const float* gamma = (const float*)d_in[7];

    short* qo = (short*)d_ws;                         // [B][N][16] bf16 (padded)
    short* ko = qo + (size_t)BATCH*NPIX*16;           // [B][N][16] bf16 (padded)
    short* vo = ko + (size_t)BATCH*NPIX*16;           // [B][C][N] bf16
    float* part = (float*)(vo + (size_t)BATCH*CCH*NPIX);  // [2048][2048] f32
    float* lp   = part + (size_t)2048*CCH*32;             // [2048][32] f32

    proj_kernel<<<BATCH*(NPIX/PXB), 256, 0, stream>>>(x, Wq, bq, Wk, bk, Wv, bv, qo, ko, vo);
    attn_main<<<BATCH*(NPIX/32)*4, 256, 0, stream>>>(qo, ko, vo, part, lp);
    merge_kernel<<<BATCH*(NPIX/32), 256, 0, stream>>>(part, lp, x, gamma, (float*)d_out);
}

// Round 12
// 101.640 us; speedup vs baseline: 1.2239x; 1.2239x over previous
//
#include <hip/hip_runtime.h>
#include <hip/hip_bf16.h>
#include <stdint.h>

#define BATCH 4
#define CCH   64
#define NPIX  4096
#define DQK   8
#define PXB   128

typedef __attribute__((ext_vector_type(8)))  short bf16x8;
typedef __attribute__((ext_vector_type(16))) float f32x16;
typedef __attribute__((ext_vector_type(4)))  uint32_t u32x4;

static __device__ __forceinline__ short f2bf(float f) {
    union { __hip_bfloat16 h; short s; } u;
    u.h = __float2bfloat16(f);
    return u.s;
}
static __device__ __forceinline__ uint32_t cvt_pk_bf16(float lo, float hi) {
    uint32_t r;
    asm("v_cvt_pk_bf16_f32 %0, %1, %2" : "=v"(r) : "v"(lo), "v"(hi));
    return r;
}

// ---------------------------------------------------------------------------
// Projection: q = (Wq x + bq)*scale*log2e, k = Wk x + bk, v = Wv x + bv
// q,k: [B][N][16] bf16 (dims 8..15 zero); v: [B][C][N] bf16.
// ---------------------------------------------------------------------------
__global__ __launch_bounds__(256) void proj_kernel(
    const float* __restrict__ x,
    const float* __restrict__ Wq, const float* __restrict__ bq,
    const float* __restrict__ Wk, const float* __restrict__ bk,
    const float* __restrict__ Wv, const float* __restrict__ bv,
    short* __restrict__ qo, short* __restrict__ ko, short* __restrict__ vo)
{
    __shared__ float xs[CCH][PXB];     // 32 KB
    __shared__ float wv_s[CCH][68];    // transposed [c][e], padded rows
    __shared__ float wq_s[CCH][DQK];
    __shared__ float wk_s[CCH][DQK];

    const int b  = blockIdx.x >> 5;
    const int n0 = (blockIdx.x & 31) * PXB;
    const int tid = threadIdx.x;

    for (int i = tid; i < CCH*CCH; i += 256) wv_s[i & 63][i >> 6] = Wv[i];
    for (int i = tid; i < CCH*DQK; i += 256) { wq_s[i & 63][i >> 6] = Wq[i]; wk_s[i & 63][i >> 6] = Wk[i]; }
    for (int i = tid; i < CCH*PXB; i += 256) {
        int c = i >> 7, p = i & 127;
        xs[c][p] = x[((size_t)b*CCH + c)*NPIX + n0 + p];
    }
    __syncthreads();

    const int p0 = tid & 31;
    const int g  = tid >> 5;       // 0..7: 8 v-channels + 1 q-dim + 1 k-dim
    const int e0 = g * 8;

    float av[4][8];
    float aq[4], ak[4];
    #pragma unroll
    for (int pi = 0; pi < 4; ++pi) {
        #pragma unroll
        for (int i = 0; i < 8; ++i) av[pi][i] = bv[e0 + i];
        aq[pi] = bq[g]; ak[pi] = bk[g];
    }

    for (int c = 0; c < CCH; ++c) {
        float4 w0 = *(const float4*)&wv_s[c][e0];
        float4 w1 = *(const float4*)&wv_s[c][e0 + 4];
        float wq = wq_s[c][g], wk = wk_s[c][g];
        #pragma unroll
        for (int pi = 0; pi < 4; ++pi) {
            float xv = xs[c][p0 + 32*pi];
            av[pi][0] += w0.x*xv; av[pi][1] += w0.y*xv;
            av[pi][2] += w0.z*xv; av[pi][3] += w0.w*xv;
            av[pi][4] += w1.x*xv; av[pi][5] += w1.y*xv;
            av[pi][6] += w1.z*xv; av[pi][7] += w1.w*xv;
            aq[pi] += wq*xv; ak[pi] += wk*xv;
        }
    }

    const float qscale = 0.51010407112635f;  // (1/sqrt(8)) * log2(e)
    const size_t vb = (size_t)b * CCH * NPIX;
    #pragma unroll
    for (int pi = 0; pi < 4; ++pi) {
        const int px = n0 + p0 + 32*pi;
        #pragma unroll
        for (int i = 0; i < 8; ++i)
            vo[vb + (size_t)(e0 + i)*NPIX + px] = f2bf(av[pi][i]);
        const size_t qb = ((size_t)b*NPIX + px)*16 + g;
        qo[qb]     = f2bf(aq[pi] * qscale);
        qo[qb + 8] = 0;
        ko[qb]     = f2bf(ak[pi]);
        ko[qb + 8] = 0;
    }
}

// ---------------------------------------------------------------------------
// Attention: 512 blocks x 512 thr (8 waves). Block = (batch, 32-query tile),
// covers ALL 4096 j via 16 windows of 256. V window [64c][256j] staged
// COALESCED global->LDS with XOR swizzle byte^=((row&15)<<4) on both write
// and read (b128 bandwidth floor both sides) -- replaces the 8KB-stride
// uncoalesced V loads (64 lines/instr) that bound R4-R11. Wave w computes
// j-subtile w*32 of each window. K+V next window prefetched to regs before
// the barrier (T14). No max tracking (bounded scores, exp2 domain).
// In-block 8-wave merge reuses the staging LDS; no part buffers.
// ---------------------------------------------------------------------------
__global__ __launch_bounds__(512, 4) void attn_kernel(
    const short* __restrict__ qg, const short* __restrict__ kg,
    const short* __restrict__ vg,
    const float* __restrict__ x, const float* __restrict__ gamma,
    float* __restrict__ outp)
{
    __shared__ __align__(16) char smem[32768];   // V window | merge buf
    __shared__ float l_s[8][32];
    __shared__ float linv_s[32];

    char*  vs_c = smem;
    float* mbuf = (float*)smem;                  // [4][64][32] f32

    const int qt = blockIdx.x & 127;
    const int b  = blockIdx.x >> 7;
    const int i0 = qt << 5;
    const int tid  = threadIdx.x;
    const int wave = tid >> 6, lane = tid & 63;
    const int hi = lane >> 5, li = lane & 31;

    f32x16 z16;
    #pragma unroll
    for (int r = 0; r < 16; ++r) z16[r] = 0.f;

    // Q fragment (B-operand): col=li, k=hi*8+e (k=8..15 stored zeros)
    const bf16x8 qf = *(const bf16x8*)&qg[((size_t)b*NPIX + i0 + li)*16 + hi*8];

    f32x16 acc0 = z16, acc1 = z16;
    float l_run = 0.f;

    const short* kp = kg + (size_t)b * NPIX * 16;
    const size_t vbase = (size_t)b * CCH * NPIX;

    // --- staging thread map: thread t loads row sc = t>>3, 16 B at j-slot t&7
    const int sc  = tid >> 3;
    const short* vsrc = vg + vbase + (size_t)sc*NPIX + (tid & 7)*8;
    const int   wb  = (tid & 7) * 16;            // byte base within row
    const int   swz = (sc & 15) << 4;
    char* wp = vs_c + sc*512;

    // --- read map: rows li / li+32, byte offset (wave*64 + hi*16) (^ swz)
    const int  rswz = (li & 15) << 4;
    const int  rb0  = (wave << 6) + (hi << 4);
    char* rp0 = vs_c + li*512;
    char* rp1 = vs_c + (li + 32)*512;

    // prologue: window 0 V-chunk + K fragment into regs
    int4 st0 = *(const int4*)(vsrc);
    int4 st1 = *(const int4*)(vsrc + 64);
    int4 st2 = *(const int4*)(vsrc + 128);
    int4 st3 = *(const int4*)(vsrc + 192);
    bf16x8 akf = *(const bf16x8*)&kp[(size_t)((wave << 5) + li)*16 + hi*8];

    for (int win = 0; win < 16; ++win) {
        // write staged window to LDS (swizzled; b128, bank-uniform)
        *(int4*)(wp + ((wb +   0) ^ swz)) = st0;
        *(int4*)(wp + ((wb + 128) ^ swz)) = st1;
        *(int4*)(wp + ((wb + 256) ^ swz)) = st2;
        *(int4*)(wp + ((wb + 384) ^ swz)) = st3;
        // issue next window's global loads (land during compute)
        if (win < 15) {
            const short* ns = vsrc + (win + 1)*256;
            st0 = *(const int4*)(ns);
            st1 = *(const int4*)(ns + 64);
            st2 = *(const int4*)(ns + 128);
            st3 = *(const int4*)(ns + 192);
        }
        __syncthreads();

        f32x16 S = __builtin_amdgcn_mfma_f32_32x32x16_bf16(akf, qf, z16, 0, 0, 0);
        // lane holds S[j][i]: col i=li, rows j=(r&3)+8*(r>>2)+4*hi (j local)
        if (win < 15) {
            const int jn = ((win + 1) << 8) + (wave << 5);
            akf = *(const bf16x8*)&kp[(size_t)(jn + li)*16 + hi*8];
        }

        // V fragments from LDS (swizzled read, bank-uniform)
        bf16x8 av00 = *(const bf16x8*)(rp0 + ((rb0     ) ^ rswz));
        bf16x8 av01 = *(const bf16x8*)(rp0 + ((rb0 + 32) ^ rswz));
        bf16x8 av10 = *(const bf16x8*)(rp1 + ((rb0     ) ^ rswz));
        bf16x8 av11 = *(const bf16x8*)(rp1 + ((rb0 + 32) ^ rswz));

        #pragma unroll
        for (int r = 0; r < 16; ++r) S[r] = __builtin_amdgcn_exp2f(S[r]);

        // lane-local l partial via add tree
        {
            float s0 = (S[0]+S[1]) + (S[2]+S[3]);
            float s1 = (S[4]+S[5]) + (S[6]+S[7]);
            float s2 = (S[8]+S[9]) + (S[10]+S[11]);
            float s3 = (S[12]+S[13]) + (S[14]+S[15]);
            l_run += (s0+s1) + (s2+s3);
        }

        // pack P -> bf16 B-fragments via cvt_pk + permlane32_swap
        uint32_t a01 = cvt_pk_bf16(S[0], S[1]);
        uint32_t a23 = cvt_pk_bf16(S[2], S[3]);
        uint32_t a45 = cvt_pk_bf16(S[4], S[5]);
        uint32_t a67 = cvt_pk_bf16(S[6], S[7]);
        uint32_t a89 = cvt_pk_bf16(S[8], S[9]);
        uint32_t aab = cvt_pk_bf16(S[10], S[11]);
        uint32_t acd = cvt_pk_bf16(S[12], S[13]);
        uint32_t aef = cvt_pk_bf16(S[14], S[15]);
        asm("v_permlane32_swap_b32 %0, %1" : "+v"(a01), "+v"(a45));
        asm("v_permlane32_swap_b32 %0, %1" : "+v"(a23), "+v"(a67));
        asm("v_permlane32_swap_b32 %0, %1" : "+v"(a89), "+v"(acd));
        asm("v_permlane32_swap_b32 %0, %1" : "+v"(aab), "+v"(aef));
        u32x4 pw0 = { a01, a23, a45, a67 };
        u32x4 pw1 = { a89, aab, acd, aef };
        bf16x8 b0 = __builtin_bit_cast(bf16x8, pw0);
        bf16x8 b1 = __builtin_bit_cast(bf16x8, pw1);

        __builtin_amdgcn_s_setprio(1);
        acc0 = __builtin_amdgcn_mfma_f32_32x32x16_bf16(av00, b0, acc0, 0, 0, 0);
        acc1 = __builtin_amdgcn_mfma_f32_32x32x16_bf16(av10, b0, acc1, 0, 0, 0);
        acc0 = __builtin_amdgcn_mfma_f32_32x32x16_bf16(av01, b1, acc0, 0, 0, 0);
        acc1 = __builtin_amdgcn_mfma_f32_32x32x16_bf16(av11, b1, acc1, 0, 0, 0);
        __builtin_amdgcn_s_setprio(0);
        __syncthreads();
    }

    // ---- in-block 8-wave merge (staging LDS reused as 4 x [64][32]) ----
    l_run += __shfl_xor(l_run, 32);
    if (hi == 0) l_s[wave][li] = l_run;

    if (wave < 4) {
        #pragma unroll
        for (int r = 0; r < 16; ++r) {
            int row = (r & 3) + ((r >> 2) << 3) + (hi << 2);
            mbuf[(wave*64 + row)*32 + li]      = acc0[r];
            mbuf[(wave*64 + row + 32)*32 + li] = acc1[r];
        }
    }
    __syncthreads();
    if (wave >= 4) {
        #pragma unroll
        for (int r = 0; r < 16; ++r) {
            int row = (r & 3) + ((r >> 2) << 3) + (hi << 2);
            mbuf[((wave-4)*64 + row)*32 + li]      += acc0[r];
            mbuf[((wave-4)*64 + row + 32)*32 + li] += acc1[r];
        }
    } else if (tid < 32) {
        float L = 0.f;
        #pragma unroll
        for (int w = 0; w < 8; ++w) L += l_s[w][tid];
        linv_s[tid] = __builtin_amdgcn_rcpf(L);
    }
    __syncthreads();

    const float g0 = gamma[0];
    for (int idx = tid; idx < CCH*32; idx += 512) {
        int c = idx >> 5, i = idx & 31;
        float s = mbuf[c*32 + i] + mbuf[(64 + c)*32 + i]
                + mbuf[(128 + c)*32 + i] + mbuf[(192 + c)*32 + i];
        size_t gidx = vbase + (size_t)c*NPIX + i0 + i;
        outp[gidx] = g0 * (s * linv_s[i]) + x[gidx];
    }
}

extern "C" void kernel_launch(void* const* d_in, const int* in_sizes, int n_in,
                              void* d_out, int out_size, void* d_ws, size_t ws_size,
                              hipStream_t stream) {
    const float* x     = (const float*)d_in[0];
    const float* Wq    = (const float*)d_in[1];
    const float* bq    = (const float*)d_in[2];
    const float* Wk    = (const float*)d_in[3];
    const float* bk    = (const float*)d_in[4];
    const float* Wv    = (const float*)d_in[5];
    const float* bv    = (const float*)d_in[6];
    const float* gamma = (const float*)d_in[7];

    short* qo = (short*)d_ws;                         // [B][N][16] bf16 (padded)
    short* ko = qo + (size_t)BATCH*NPIX*16;           // [B][N][16] bf16 (padded)
    short* vo = ko + (size_t)BATCH*NPIX*16;           // [B][C][N] bf16

    proj_kernel<<<BATCH*(NPIX/PXB), 256, 0, stream>>>(x, Wq, bq, Wk, bk, Wv, bv, qo, ko, vo);
    attn_kernel<<<BATCH*(NPIX/32), 512, 0, stream>>>(qo, ko, vo, x, gamma, (float*)d_out);
}